// Round 8
// baseline (219.548 us; speedup 1.0000x reference)
//
#include <hip/hip_runtime.h>
#include <hip/hip_bf16.h>
#include <hip/hip_fp16.h>
#include <math.h>

#define NK 256
#define NT 128
#define NC 32
#define ND 10
#define NSPK 1000000
#define LOG2PI 1.8378770664093453f
#define NWCHUNK (NSPK / 64)            // 15625 wave-chunks (exact)
#define SGRID ((NWCHUNK + 3) / 4)      // 3907 one-shot blocks, 4 waves each

#define FSTR 36                        // dwords per feat row: 144 B, 16B-aligned
#define WAVE_LDS (64 * FSTR + 128)     // + 64 x {kt, s9sq} side table

typedef __attribute__((ext_vector_type(8))) short short8;
typedef __attribute__((ext_vector_type(4))) float floatx4;
typedef __attribute__((ext_vector_type(4))) int intx4;
typedef __attribute__((ext_vector_type(2))) int intx2;

union FragCvt { intx4 i; short8 s; };
union LpCvt { intx2 i2; __half2 h2[2]; };

// ws layout:
//   [0,8)      double acc
//   [8,12)     uint done-counter
//   [64,320)   float cpack[64] : [c]=cst_c, [32+c]=w99_c
//   [1024,..)  int wt[64][32]  : bf16-pair-packed W, rows 0..31 hi, 32..63 lo
//   [16384,..) __half pisT[NK*NT][32] : fp16 (log_pi + cst), 64 B rows

__device__ inline unsigned pack_bf16(float a, float b) {
  __hip_bfloat16 ha = __float2bfloat16(a), hb = __float2bfloat16(b);
  unsigned short ua, ub;
  __builtin_memcpy(&ua, &ha, 2);
  __builtin_memcpy(&ub, &hb, 2);
  return (unsigned)ua | ((unsigned)ub << 16);
}

// ============================ PREP 1: coefs + scalars ======================
__global__ void prep1_kernel(const float* __restrict__ means,
                             const float* __restrict__ covs,
                             const float* __restrict__ b_mu,
                             const float* __restrict__ b_ls,
                             const float* __restrict__ beta_mu,
                             const float* __restrict__ beta_ls,
                             int* __restrict__ wt,
                             float* __restrict__ cpack,
                             double* __restrict__ acc,
                             unsigned int* __restrict__ counter) {
  int blk = blockIdx.x;
  int tid = threadIdx.x;

  if (blk == 0) {
    int c = tid;
    if (c >= NC) return;

    float M[ND][ND];
    #pragma unroll
    for (int i = 0; i < ND; ++i)
      #pragma unroll
      for (int j = 0; j < ND; ++j)
        M[i][j] = covs[c * ND * ND + i * ND + j];

    // Cholesky, lower triangle in place
    float logdet = 0.f;
    #pragma unroll
    for (int j = 0; j < ND; ++j) {
      float d = M[j][j];
      #pragma unroll
      for (int k = 0; k < ND; ++k) if (k < j) d -= M[j][k] * M[j][k];
      float sq = sqrtf(d);
      M[j][j] = sq;
      logdet += 2.f * __logf(sq);
      float inv = 1.f / sq;
      #pragma unroll
      for (int i = 0; i < ND; ++i) {
        if (i > j) {
          float s2 = M[i][j];
          #pragma unroll
          for (int k = 0; k < ND; ++k) if (k < j) s2 -= M[i][k] * M[j][k];
          M[i][j] = s2 * inv;
        }
      }
    }

    // invert lower triangle in place: M(lower) := L^-1
    #pragma unroll
    for (int j = 0; j < ND; ++j) {
      M[j][j] = 1.f / M[j][j];
      #pragma unroll
      for (int i = 0; i < ND; ++i) {
        if (i > j) {
          float s2 = 0.f;
          #pragma unroll
          for (int k = 0; k < ND; ++k) if (k >= j && k < i) s2 += M[i][k] * M[k][j];
          M[i][j] = -s2 / M[i][i];
        }
      }
    }

    // P = Li^T Li : off-diag -> upper triangle of M, diag -> pd[]
    float pd[ND];
    #pragma unroll
    for (int i = 0; i < ND; ++i) {
      #pragma unroll
      for (int jj = 0; jj < ND; ++jj) {
        if (jj >= i) {
          float s2 = 0.f;
          #pragma unroll
          for (int k = 0; k < ND; ++k) if (k >= jj) s2 += M[k][i] * M[k][jj];
          if (jj > i) M[i][jj] = s2;
          else pd[i] = s2;
        }
      }
    }

    float mu[ND], qv[ND];
    #pragma unroll
    for (int i = 0; i < ND; ++i) mu[i] = means[c * ND + i];
    float muPmu = 0.f;
    #pragma unroll
    for (int i = 0; i < ND; ++i) {
      float a2 = pd[i] * mu[i];
      #pragma unroll
      for (int j = 0; j < ND; ++j) {
        if (j < i) a2 += M[j][i] * mu[j];
        if (j > i) a2 += M[i][j] * mu[j];
      }
      qv[i] = a2;
      muPmu += mu[i] * a2;
    }
    float cst = -0.5f * ((float)ND * LOG2PI + logdet + muPmu);

    // K=64 coefficient vector: 54 pairs (i<=j except (9,9)) + 10 linear
    float wv[64];
    int p = 0;
    #pragma unroll
    for (int i = 0; i < ND; ++i)
      #pragma unroll
      for (int j = 0; j < ND; ++j)
        if (j >= i && !(i == 9 && j == 9))
          wv[p++] = (i == j) ? -0.5f * pd[i] : -M[i][j];
    #pragma unroll
    for (int i = 0; i < ND; ++i) wv[54 + i] = qv[i];

    // hi/lo split, bf16-pair pack; rows of 32 dwords (128B)
    #pragma unroll
    for (int j = 0; j < 32; ++j) {
      float a = wv[2 * j], b = wv[2 * j + 1];
      float ah = __bfloat162float(__float2bfloat16(a));
      float bh = __bfloat162float(__float2bfloat16(b));
      wt[c * 32 + j] = (int)pack_bf16(ah, bh);
      wt[(32 + c) * 32 + j] = (int)pack_bf16(a - ah, b - bh);
    }
    cpack[c] = cst;
    cpack[32 + c] = -0.5f * pd[9];   // w99

  } else {
    // prior - q scalar terms -> plain-store acc, init counter
    float local = 0.f;
    for (int i = tid; i < NC; i += 256)
      local += fmaf(-0.5f * b_mu[i], b_mu[i], b_ls[i]);
    for (int i = tid; i < NC * NT; i += 256)
      local += fmaf(-0.5f * beta_mu[i], beta_mu[i], beta_ls[i]);
    #pragma unroll
    for (int off = 32; off > 0; off >>= 1) local += __shfl_down(local, off);
    __shared__ float red[4];
    if ((tid & 63) == 0) red[tid >> 6] = local;
    __syncthreads();
    if (tid == 0) {
      acc[0] = (double)(red[0] + red[1] + red[2] + red[3]);
      counter[0] = 0u;
    }
  }
}

// ============== PREP 2: log-softmax pis table w/ cst folded (fp16) =========
__global__ void prep2_kernel(const float* __restrict__ y,
                             const float* __restrict__ b_mu,
                             const float* __restrict__ beta_mu,
                             const float* __restrict__ cpack,
                             __half* __restrict__ pisT) {
  int id = blockIdx.x * 256 + threadIdx.x;   // id = k*NT + t
  int t = id & (NT - 1);
  float yv = y[id];
  float v[NC];
  float m = -1e30f;
  #pragma unroll
  for (int c = 0; c < NC; ++c) {
    v[c] = fmaf(beta_mu[c * NT + t], yv, b_mu[c]);
    m = fmaxf(m, v[c]);
  }
  float ssum = 0.f;
  #pragma unroll
  for (int c = 0; c < NC; ++c) ssum += __expf(v[c] - m);
  float lz = m + __logf(ssum);
  __half* outp = pisT + (size_t)id * NC;
  #pragma unroll
  for (int c = 0; c < NC; ++c) outp[c] = __float2half(v[c] - lz + cpack[c]);
}

// ========== MAIN: one-shot wave-autonomous MFMA, shfl epilogue =============
__global__ void __launch_bounds__(256)
__attribute__((amdgpu_waves_per_eu(4, 8)))
spike_kernel(const float* __restrict__ s,
             const int* __restrict__ ks,
             const int* __restrict__ ts,
             const int* __restrict__ wt,
             const float* __restrict__ cpack,
             const __half* __restrict__ pisT,
             double* __restrict__ acc,
             unsigned int* __restrict__ counter,
             float* __restrict__ out) {
  __shared__ int lds[4 * WAVE_LDS];
  __shared__ float red[4];

  int tid = threadIdx.x;
  int wid = tid >> 6, L = tid & 63;
  int r = L & 15, q = L >> 4;
  int* ldsw = &lds[wid * WAVE_LDS];          // 64 x FSTR feat rows
  int* ldkt = ldsw + 64 * FSTR;              // 64 x {kt, s9sq}

  int g = blockIdx.x * 4 + wid;              // one chunk per wave
  bool active = g < NWCHUNK;

  // W as MFMA A-operand: lane (r,q) holds W[mt*16+r][kk*32+q*8+j]
  FragCvt wf[2][2][2];   // [h][mt][kk]
  #pragma unroll
  for (int h = 0; h < 2; ++h)
    #pragma unroll
    for (int mt = 0; mt < 2; ++mt)
      #pragma unroll
      for (int kk = 0; kk < 2; ++kk)
        wf[h][mt][kk].i =
            *(const intx4*)&wt[(h * 32 + mt * 16 + r) * 32 + kk * 16 + q * 4];

  // per-lane w99 slice: comps mt*16 + q*4 + rr
  float4 w99f[2];
  #pragma unroll
  for (int mt = 0; mt < 2; ++mt)
    w99f[mt] = *(const float4*)&cpack[32 + mt * 16 + q * 4];

  float lse_sum = 0.f;

  if (active) {
    int n = g * 64 + L;

    // own spike row + (k,t)
    const float2* srow = (const float2*)(s + (size_t)n * ND);
    float sv[ND];
    #pragma unroll
    for (int i = 0; i < 5; ++i) {
      float2 v2 = srow[i];
      sv[2 * i] = v2.x;
      sv[2 * i + 1] = v2.y;
    }
    int kt = ks[n] * NT + ts[n];

    // publish {kt, s9sq} for cross-lane use (wave-private, in-order DS)
    {
      intx2 kp;
      kp.x = kt;
      kp.y = __float_as_int(sv[9] * sv[9]);
      *(intx2*)&ldkt[L * 2] = kp;
    }

    // build K=64 bf16 feature row -> wave-private LDS row L (stride 36)
    {
      int rb = L * FSTR;
      float f[8];
      int p = 0;
      #pragma unroll
      for (int i = 0; i < ND; ++i) {
        #pragma unroll
        for (int j = i; j < ND; ++j) {
          if (i == 9 && j == 9) continue;
          f[p & 7] = sv[i] * sv[j];
          if ((p & 7) == 7) {
            intx4 v;
            v.x = (int)pack_bf16(f[0], f[1]);
            v.y = (int)pack_bf16(f[2], f[3]);
            v.z = (int)pack_bf16(f[4], f[5]);
            v.w = (int)pack_bf16(f[6], f[7]);
            *(intx4*)&ldsw[rb + (p >> 3) * 4] = v;
          }
          ++p;
        }
      }
      #pragma unroll
      for (int i = 0; i < ND; ++i) {
        f[p & 7] = sv[i];
        if ((p & 7) == 7) {
          intx4 v;
          v.x = (int)pack_bf16(f[0], f[1]);
          v.y = (int)pack_bf16(f[2], f[3]);
          v.z = (int)pack_bf16(f[4], f[5]);
          v.w = (int)pack_bf16(f[6], f[7]);
          *(intx4*)&ldsw[rb + (p >> 3) * 4] = v;
        }
        ++p;
      }
    }

    // fetch kt/s9sq of my 4 epilogue spikes (nt*16 + r)
    int kt4[4];
    float s9sq4[4];
    #pragma unroll
    for (int nt = 0; nt < 4; ++nt) {
      intx2 kp = *(const intx2*)&ldkt[(nt * 16 + r) * 2];
      kt4[nt] = kp.x;
      s9sq4[nt] = __int_as_float(kp.y);
    }

    // issue 8 lp gathers early (consumed after MFMA): comps mt*16+q*4+{0..3}
    intx2 lraw[4][2];
    const char* ptbase = (const char*)pisT;
    #pragma unroll
    for (int nt = 0; nt < 4; ++nt)
      #pragma unroll
      for (int mt = 0; mt < 2; ++mt)
        lraw[nt][mt] = *(const intx2*)(ptbase + (size_t)kt4[nt] * 64 +
                                       mt * 32 + q * 8);

    // MFMA: D[comp][spike] = W x F
    floatx4 accf[2][4];   // [mt][nt]
    #pragma unroll
    for (int mt = 0; mt < 2; ++mt)
      #pragma unroll
      for (int nt = 0; nt < 4; ++nt)
        accf[mt][nt] = (floatx4){0.f, 0.f, 0.f, 0.f};

    #pragma unroll
    for (int nt = 0; nt < 4; ++nt) {
      FragCvt b0, b1;
      b0.i = *(const intx4*)&ldsw[(nt * 16 + r) * FSTR + q * 4];
      b1.i = *(const intx4*)&ldsw[(nt * 16 + r) * FSTR + 16 + q * 4];
      #pragma unroll
      for (int mt = 0; mt < 2; ++mt) {
        accf[mt][nt] = __builtin_amdgcn_mfma_f32_16x16x32_bf16(
            wf[0][mt][0].s, b0.s, accf[mt][nt], 0, 0, 0);
        accf[mt][nt] = __builtin_amdgcn_mfma_f32_16x16x32_bf16(
            wf[1][mt][0].s, b0.s, accf[mt][nt], 0, 0, 0);
        accf[mt][nt] = __builtin_amdgcn_mfma_f32_16x16x32_bf16(
            wf[0][mt][1].s, b1.s, accf[mt][nt], 0, 0, 0);
        accf[mt][nt] = __builtin_amdgcn_mfma_f32_16x16x32_bf16(
            wf[1][mt][1].s, b1.s, accf[mt][nt], 0, 0, 0);
      }
    }

    // epilogue in C-layout: per nt, lane holds 8 comps of spike nt*16+r;
    // butterfly over the 4 q-lanes completes the 32-comp logsumexp.
    #pragma unroll
    for (int nt = 0; nt < 4; ++nt) {
      float lg[2][4];
      #pragma unroll
      for (int mt = 0; mt < 2; ++mt) {
        LpCvt lc;
        lc.i2 = lraw[nt][mt];
        float lp0 = __low2float(lc.h2[0]), lp1 = __high2float(lc.h2[0]);
        float lp2 = __low2float(lc.h2[1]), lp3 = __high2float(lc.h2[1]);
        lg[mt][0] = accf[mt][nt][0] + lp0 + w99f[mt].x * s9sq4[nt];
        lg[mt][1] = accf[mt][nt][1] + lp1 + w99f[mt].y * s9sq4[nt];
        lg[mt][2] = accf[mt][nt][2] + lp2 + w99f[mt].z * s9sq4[nt];
        lg[mt][3] = accf[mt][nt][3] + lp3 + w99f[mt].w * s9sq4[nt];
      }
      float m = lg[0][0];
      #pragma unroll
      for (int mt = 0; mt < 2; ++mt)
        #pragma unroll
        for (int rr = 0; rr < 4; ++rr) m = fmaxf(m, lg[mt][rr]);
      m = fmaxf(m, __shfl_xor(m, 16));
      m = fmaxf(m, __shfl_xor(m, 32));
      float ssum = 0.f;
      #pragma unroll
      for (int mt = 0; mt < 2; ++mt)
        #pragma unroll
        for (int rr = 0; rr < 4; ++rr) ssum += __expf(lg[mt][rr] - m);
      ssum += __shfl_xor(ssum, 16);
      ssum += __shfl_xor(ssum, 32);
      float lse = m + __logf(ssum);
      lse_sum += (q == 0) ? lse : 0.f;
    }
  }

  // block reduction -> one fp64 atomic per block
  #pragma unroll
  for (int off = 32; off > 0; off >>= 1) lse_sum += __shfl_down(lse_sum, off);
  if ((tid & 63) == 0) red[tid >> 6] = lse_sum;
  __syncthreads();
  if (tid == 0) {
    atomicAdd(acc, (double)(red[0] + red[1] + red[2] + red[3]));
    __threadfence();
    unsigned int old = atomicAdd(counter, 1u);
    if (old == SGRID - 1) {
      __threadfence();
      double v = atomicAdd(acc, 0.0);
      out[0] = (float)v;
    }
  }
}

extern "C" void kernel_launch(void* const* d_in, const int* in_sizes, int n_in,
                              void* d_out, int out_size, void* d_ws, size_t ws_size,
                              hipStream_t stream) {
  const float* s       = (const float*)d_in[0];
  const float* y       = (const float*)d_in[1];
  const int*   ks      = (const int*)d_in[2];
  const int*   ts      = (const int*)d_in[3];
  const float* means   = (const float*)d_in[4];
  const float* covs    = (const float*)d_in[5];
  const float* b_mu    = (const float*)d_in[6];
  const float* b_ls    = (const float*)d_in[7];
  const float* beta_mu = (const float*)d_in[8];
  const float* beta_ls = (const float*)d_in[9];
  float* out = (float*)d_out;

  char* ws = (char*)d_ws;
  double* acc           = (double*)ws;
  unsigned int* counter = (unsigned int*)(ws + 8);
  float* cpack          = (float*)(ws + 64);
  int* wt               = (int*)(ws + 1024);
  __half* pisT          = (__half*)(ws + 16384);

  prep1_kernel<<<2, 256, 0, stream>>>(
      means, covs, b_mu, b_ls, beta_mu, beta_ls, wt, cpack, acc, counter);
  prep2_kernel<<<(NK * NT) / 256, 256, 0, stream>>>(
      y, b_mu, beta_mu, cpack, pisT);
  spike_kernel<<<SGRID, 256, 0, stream>>>(
      s, ks, ts, wt, cpack, pisT, acc, counter, out);
}